// Round 1
// baseline (274.622 us; speedup 1.0000x reference)
//
#include <hip/hip_runtime.h>
#include <hip/hip_bf16.h>
#include <math.h>

// ---------------------------------------------------------------------------
// Hybrid fused transformer block (R8 = R7 + numerics hardening):
//   - MFMA (split-4 bf16, fp32-grade) for Q/K/V projections, FFN1, FFN2
//   - SCALAR fp32 attention (R2-verbatim: lane=token, chunk-8 online softmax)
//   - TWO-PASS variance in LN1/LN2 (matches reference mean(square(x-mu)));
//     the one-pass E[x^2]-mu^2 form cancels catastrophically on low-variance
//     rows where rstd ~ 1/sqrt(eps) amplifies var error ~300x into the output.
// One wave (64 threads) per batch block of 64 tokens x 16 channels.
// v_mfma_f32_16x16x32_bf16 layouts (m89/m91-verified):
//   C/D: col=lane&15, row=(lane>>4)*4+reg
//   A:   A[m=lane&15][k=(lane>>4)*8+j]
//   B:   B[k=(lane>>4)*8+j][n=lane&15]
// Only phase-level cross-lane LDS hand-offs, each guarded by __syncthreads().
// ---------------------------------------------------------------------------

typedef __attribute__((ext_vector_type(8))) short bf8;   // 8 bf16 (4 VGPRs)
typedef __attribute__((ext_vector_type(4))) float f4;    // 4 fp32 (C/D frag)

union FragU { uint4 u4; uint u[4]; bf8 b; };

__device__ __forceinline__ uint packbf(float lo, float hi) {   // v_cvt_pk_bf16_f32
    union { __hip_bfloat162 h; uint u; } c;
    c.h = __float22bfloat162_rn(make_float2(lo, hi));
    return c.u;
}
// split pair (a,b) into bf16-hi word + bf16-lo(residual) word
__device__ __forceinline__ void split2(float a, float b, uint& h, uint& l) {
    h = packbf(a, b);
    float ra = a - __uint_as_float(h << 16);          // exact residual
    float rb = b - __uint_as_float(h & 0xFFFF0000u);
    l = packbf(ra, rb);
}

// exact-gelu via A&S 7.1.26 erf (max err 1.5e-7), branch-free
__device__ __forceinline__ float gelu_f(float u) {
    float z  = fabsf(u) * 0.70710678118654752f;
    float tt = __builtin_amdgcn_rcpf(1.f + 0.3275911f * z);
    float poly = ((((1.061405429f * tt - 1.453152027f) * tt + 1.421413741f) * tt
                   - 0.284496736f) * tt + 0.254829592f) * tt;
    float erfz = 1.f - poly * __expf(-z * z);
    return 0.5f * u * (1.f + copysignf(erfz, u));
}

#define MFMA(a, b, c) __builtin_amdgcn_mfma_f32_16x16x32_bf16(a, b, c, 0, 0, 0)

// LDS arena (uint/float units), 3328 words = 13312 B.
//  Phase A: sQ f32[64][20]@0, sK f32[64][16]@1280, sV f32[64][16]@2304
//  Phase C: sH2 bf16 hi+lo [64][20]@0        (over dead sQ; per-lane rows)
//  Phase D: sU  bf16 hi+lo [64][36]@0        (over dead sH2/sK)
//  Phase E: sFFN f32[64][17]@0               (over dead sU head)
#define O_SQ   0
#define O_SK   1280
#define O_SV   2304
#define O_SH2  0
#define O_SU   0
#define O_SFFN 0
#define ARENA  3328

// hi/lo split B-fragment pair: B[k=kb+j][n], row-major W, leading dim ld
__device__ __forceinline__ void loadWfragHL(const float* __restrict__ W, int ld,
                                            int n, int kb, bool valid, float scale,
                                            bf8& hf, bf8& lf) {
    FragU H, L;
    if (valid) {
        #pragma unroll
        for (int p = 0; p < 4; ++p) {
            float a = W[(kb+2*p  )*ld+n]*scale;
            float b = W[(kb+2*p+1)*ld+n]*scale;
            split2(a, b, H.u[p], L.u[p]);
        }
    } else {
        H.u4 = make_uint4(0u,0u,0u,0u);
        L.u4 = H.u4;
    }
    hf = H.b; lf = L.b;
}

__global__ __launch_bounds__(64, 3)
void tb_kernel(const float* __restrict__ x,
               const float* __restrict__ Wk, const float* __restrict__ Wq,
               const float* __restrict__ Wv,
               const float* __restrict__ ln1g, const float* __restrict__ ln1b,
               const float* __restrict__ ln2g, const float* __restrict__ ln2b,
               const float* __restrict__ W1, const float* __restrict__ b1,
               const float* __restrict__ W2, const float* __restrict__ b2,
               float* __restrict__ out)
{
    __shared__ __align__(16) uint lds[ARENA];
    float* ldsF = (float*)lds;
    const int lane = threadIdx.x;
    const int c15  = lane & 15;
    const int quad = lane >> 4;
    const size_t base = (size_t)blockIdx.x * (64 * 16);
    const f4 z4 = {0.f, 0.f, 0.f, 0.f};
    const bool kv = (quad < 2);          // K=16 mats: only quads 0,1 carry data
    const int  kb = quad * 8;

    // ---- attention weight fragments (split hi/lo)
    bf8 fWq_h, fWq_l, fWk_h, fWk_l, fWv_h, fWv_l;
    loadWfragHL(Wq, 16, c15, kb, kv, 0.25f, fWq_h, fWq_l);  // fold 1/sqrt(D)
    loadWfragHL(Wk, 16, c15, kb, kv, 1.0f,  fWk_h, fWk_l);
    loadWfragHL(Wv, 16, c15, kb, kv, 1.0f,  fWv_h, fWv_l);

    // ---- LN1 (fp32, TWO-PASS variance) -> split hi/lo A-fragments
    bf8 ah_h[4], ah_l[4];
    {
        float gg[8], bb[8];
        if (kv) {
            const float4* gp = (const float4*)(ln1g + kb);
            const float4* bp = (const float4*)(ln1b + kb);
            float4 g0 = gp[0], g1 = gp[1], b0 = bp[0], b1_ = bp[1];
            gg[0]=g0.x; gg[1]=g0.y; gg[2]=g0.z; gg[3]=g0.w;
            gg[4]=g1.x; gg[5]=g1.y; gg[6]=g1.z; gg[7]=g1.w;
            bb[0]=b0.x; bb[1]=b0.y; bb[2]=b0.z; bb[3]=b0.w;
            bb[4]=b1_.x; bb[5]=b1_.y; bb[6]=b1_.z; bb[7]=b1_.w;
        }
        #pragma unroll
        for (int mt = 0; mt < 4; ++mt) {
            FragU Ah, Al;
            if (kv) {
                const float4* xp = (const float4*)(x + base + (size_t)(mt*16 + c15)*16 + kb);
                float4 v0 = xp[0], v1 = xp[1];
                float xv[8] = {v0.x,v0.y,v0.z,v0.w, v1.x,v1.y,v1.z,v1.w};
                float s = 0.f;
                #pragma unroll
                for (int j = 0; j < 8; ++j) s += xv[j];
                s  += __shfl_xor(s, 16);    // combine half-rows (both in quads 0,1)
                float mu = s * 0.0625f;
                float s2 = 0.f;
                #pragma unroll
                for (int j = 0; j < 8; ++j) { float d = xv[j] - mu; s2 += d*d; }
                s2 += __shfl_xor(s2, 16);   // two-pass variance: no cancellation
                float var  = s2 * 0.0625f;
                float rstd = rsqrtf(var + 1e-5f);
                float h[8];
                #pragma unroll
                for (int j = 0; j < 8; ++j) h[j] = (xv[j]-mu)*rstd*gg[j] + bb[j];
                #pragma unroll
                for (int p = 0; p < 4; ++p) split2(h[2*p], h[2*p+1], Ah.u[p], Al.u[p]);
            } else {
                Ah.u4 = make_uint4(0u,0u,0u,0u);
                Al.u4 = Ah.u4;
            }
            ah_h[mt] = Ah.b; ah_l[mt] = Al.b;
        }
    }

    // ---- projections (split-4): Q,K,V stored fp32 row-major [token][ch]
    #pragma unroll
    for (int mt = 0; mt < 4; ++mt) {
        f4 qc = MFMA(ah_l[mt], fWq_l, z4);      // smallest term first
        qc = MFMA(ah_l[mt], fWq_h, qc);
        qc = MFMA(ah_h[mt], fWq_l, qc);
        qc = MFMA(ah_h[mt], fWq_h, qc);
        f4 kc = MFMA(ah_l[mt], fWk_l, z4);
        kc = MFMA(ah_l[mt], fWk_h, kc);
        kc = MFMA(ah_h[mt], fWk_l, kc);
        kc = MFMA(ah_h[mt], fWk_h, kc);
        f4 vc = MFMA(ah_l[mt], fWv_l, z4);
        vc = MFMA(ah_l[mt], fWv_h, vc);
        vc = MFMA(ah_h[mt], fWv_l, vc);
        vc = MFMA(ah_h[mt], fWv_h, vc);
        const int rowb = mt*16 + quad*4;
        #pragma unroll
        for (int r = 0; r < 4; ++r) {
            ldsF[O_SQ + (rowb + r)*20 + c15] = qc[r];
            ldsF[O_SK + (rowb + r)*16 + c15] = kc[r];
            ldsF[O_SV + (rowb + r)*16 + c15] = vc[r];
        }
    }
    __syncthreads();   // B1: Q/K/V visible

    // ---- SCALAR attention (R2-proven): lane = token t
    float qr[16];
    {
        const float4* qp = (const float4*)(ldsF + O_SQ + lane*20);  // 80B rows, aligned
        float4 a = qp[0], b = qp[1], c = qp[2], d = qp[3];
        qr[0]=a.x; qr[1]=a.y; qr[2]=a.z;  qr[3]=a.w;
        qr[4]=b.x; qr[5]=b.y; qr[6]=b.z;  qr[7]=b.w;
        qr[8]=c.x; qr[9]=c.y; qr[10]=c.z; qr[11]=c.w;
        qr[12]=d.x;qr[13]=d.y;qr[14]=d.z; qr[15]=d.w;
    }
    float xs[16];
    {
        const float4* xp = (const float4*)(x + base + (size_t)lane * 16);
        float4 a = xp[0], b = xp[1], c = xp[2], d = xp[3];
        xs[0]=a.x; xs[1]=a.y; xs[2]=a.z;  xs[3]=a.w;
        xs[4]=b.x; xs[5]=b.y; xs[6]=b.z;  xs[7]=b.w;
        xs[8]=c.x; xs[9]=c.y; xs[10]=c.z; xs[11]=c.w;
        xs[12]=d.x;xs[13]=d.y;xs[14]=d.z; xs[15]=d.w;
    }

    float m = -1e30f, l = 0.f;
    float y[16];
    #pragma unroll
    for (int j = 0; j < 16; ++j) y[j] = 0.f;

    for (int c = 0; c < 8; ++c) {
        float sc[8];
        #pragma unroll
        for (int u = 0; u < 8; ++u) {
            const int s = c * 8 + u;
            const float4* kp = (const float4*)(ldsF + O_SK + s*16);  // broadcast
            float4 k0 = kp[0], k1 = kp[1], k2 = kp[2], k3 = kp[3];
            float d = qr[0]*k0.x + qr[1]*k0.y + qr[2]*k0.z + qr[3]*k0.w
                    + qr[4]*k1.x + qr[5]*k1.y + qr[6]*k1.z + qr[7]*k1.w
                    + qr[8]*k2.x + qr[9]*k2.y + qr[10]*k2.z + qr[11]*k2.w
                    + qr[12]*k3.x + qr[13]*k3.y + qr[14]*k3.z + qr[15]*k3.w;
            sc[u] = (s <= lane) ? d : -1e30f;     // causal (scale folded in Wq)
        }
        float cm = sc[0];
        #pragma unroll
        for (int u = 1; u < 8; ++u) cm = fmaxf(cm, sc[u]);
        float mn    = fmaxf(m, cm);
        float alpha = __expf(m - mn);
        l *= alpha;
        #pragma unroll
        for (int j = 0; j < 16; ++j) y[j] *= alpha;
        #pragma unroll
        for (int u = 0; u < 8; ++u) {
            const int s = c * 8 + u;
            float p = __expf(sc[u] - mn);
            l += p;
            const float4* vp = (const float4*)(ldsF + O_SV + s*16);  // broadcast
            float4 v0 = vp[0], v1 = vp[1], v2 = vp[2], v3 = vp[3];
            y[0]  += p*v0.x; y[1]  += p*v0.y; y[2]  += p*v0.z; y[3]  += p*v0.w;
            y[4]  += p*v1.x; y[5]  += p*v1.y; y[6]  += p*v1.z; y[7]  += p*v1.w;
            y[8]  += p*v2.x; y[9]  += p*v2.y; y[10] += p*v2.z; y[11] += p*v2.w;
            y[12] += p*v3.x; y[13] += p*v3.y; y[14] += p*v3.z; y[15] += p*v3.w;
        }
        m = mn;
    }
    float x2[16];
    {
        float rl = 1.0f / l;                      // exact IEEE division (once)
        #pragma unroll
        for (int j = 0; j < 16; ++j) x2[j] = xs[j] + y[j] * rl;   // residual 1
    }

    // ---- LN2 fully per-lane (TWO-PASS variance) -> h2 split -> sH2
    {
        float s = 0.f;
        #pragma unroll
        for (int j = 0; j < 16; ++j) s += x2[j];
        float mu = s * 0.0625f;
        float s2 = 0.f;
        #pragma unroll
        for (int j = 0; j < 16; ++j) { float d = x2[j] - mu; s2 += d*d; }
        float var  = s2 * 0.0625f;               // two-pass: no cancellation
        float rstd = rsqrtf(var + 1e-5f);
        uint hh[8], hl[8];
        #pragma unroll
        for (int jj = 0; jj < 4; ++jj) {
            float4 gv = ((const float4*)ln2g)[jj];
            float4 bv = ((const float4*)ln2b)[jj];
            float h0 = (x2[4*jj+0]-mu)*rstd*gv.x + bv.x;
            float h1 = (x2[4*jj+1]-mu)*rstd*gv.y + bv.y;
            float h2v = (x2[4*jj+2]-mu)*rstd*gv.z + bv.z;
            float h3 = (x2[4*jj+3]-mu)*rstd*gv.w + bv.w;
            split2(h0, h1, hh[2*jj],   hl[2*jj]);
            split2(h2v, h3, hh[2*jj+1], hl[2*jj+1]);
        }
        *(uint4*)(lds + O_SH2 + lane*20)      = make_uint4(hh[0],hh[1],hh[2],hh[3]);
        *(uint4*)(lds + O_SH2 + lane*20 + 4)  = make_uint4(hh[4],hh[5],hh[6],hh[7]);
        *(uint4*)(lds + O_SH2 + lane*20 + 8)  = make_uint4(hl[0],hl[1],hl[2],hl[3]);
        *(uint4*)(lds + O_SH2 + lane*20 + 12) = make_uint4(hl[4],hl[5],hl[6],hl[7]);
    }
    __syncthreads();   // B2: sH2 visible

    // ---- h2 A-fragments
    bf8 a2h[4], a2l[4];
    #pragma unroll
    for (int i = 0; i < 4; ++i) {
        FragU H, L;
        if (kv) {
            H.u4 = *(const uint4*)(lds + O_SH2 + (i*16 + c15)*20 + quad*4);
            L.u4 = *(const uint4*)(lds + O_SH2 + (i*16 + c15)*20 + 8 + quad*4);
        } else {
            H.u4 = make_uint4(0u,0u,0u,0u);
            L.u4 = H.u4;
        }
        a2h[i] = H.b; a2l[i] = L.b;
    }
    __syncthreads();   // B3: sH2 dead; sU region writable

    // ---- FFN weight fragments
    bf8 fW1a_h, fW1a_l, fW1b_h, fW1b_l, fW2_h, fW2_l;
    loadWfragHL(W1, 32, c15,      kb, kv,   1.0f, fW1a_h, fW1a_l);
    loadWfragHL(W1, 32, c15 + 16, kb, kv,   1.0f, fW1b_h, fW1b_l);
    loadWfragHL(W2, 16, c15,      kb, true, 1.0f, fW2_h,  fW2_l);

    // ---- FFN1 (split-4) + gelu -> sU hi/lo [64][36]
    {
        float bu0 = b1[c15], bu1 = b1[16 + c15];
        f4 cb0 = {bu0, bu0, bu0, bu0};
        f4 cb1 = {bu1, bu1, bu1, bu1};
        f4 uu[4][2];
        #pragma unroll
        for (int mt = 0; mt < 4; ++mt) {
            f4 u0 = MFMA(a2l[mt], fW1a_l, cb0);
            u0 = MFMA(a2l[mt], fW1a_h, u0);
            u0 = MFMA(a2h[mt], fW1a_l, u0);
            uu[mt][0] = MFMA(a2h[mt], fW1a_h, u0);
            f4 u1 = MFMA(a2l[mt], fW1b_l, cb1);
            u1 = MFMA(a2l[mt], fW1b_h, u1);
            u1 = MFMA(a2h[mt], fW1b_l, u1);
            uu[mt][1] = MFMA(a2h[mt], fW1b_h, u1);
        }
        const bool wr = ((c15 & 1) == 0);
        #pragma unroll
        for (int mt = 0; mt < 4; ++mt)
            #pragma unroll
            for (int nt = 0; nt < 2; ++nt)
                #pragma unroll
                for (int r = 0; r < 4; ++r) {
                    float g  = gelu_f(uu[mt][nt][r]);
                    float go = __shfl_xor(g, 1);
                    if (wr) {
                        uint hw, lw;
                        split2(g, go, hw, lw);
                        uint row = mt*16 + quad*4 + r;
                        lds[O_SU + row*36 +      nt*8 + (c15 >> 1)] = hw;
                        lds[O_SU + row*36 + 16 + nt*8 + (c15 >> 1)] = lw;
                    }
                }
    }
    __syncthreads();   // B4: sU visible

    // ---- FFN2 (split-4, K=32 full)
    f4 fo[4];
    {
        float bo = b2[c15];
        f4 cb = {bo, bo, bo, bo};
        #pragma unroll
        for (int mt = 0; mt < 4; ++mt) {
            FragU H, L;
            uint off = (uint)(mt*16 + c15)*36;
            H.u4 = *(const uint4*)(lds + O_SU + off +      quad*4);
            L.u4 = *(const uint4*)(lds + O_SU + off + 16 + quad*4);
            f4 f0 = MFMA(L.b, fW2_l, cb);
            f0 = MFMA(L.b, fW2_h, f0);
            f0 = MFMA(H.b, fW2_l, f0);
            fo[mt] = MFMA(H.b, fW2_h, f0);
        }
    }
    __syncthreads();   // B5: sU dead; sFFN writable
    #pragma unroll
    for (int mt = 0; mt < 4; ++mt)
        #pragma unroll
        for (int r = 0; r < 4; ++r)
            lds[O_SFFN + (mt*16 + quad*4 + r)*17 + c15] = __float_as_uint(fo[mt][r]);
    __syncthreads();   // B6: sFFN visible

    // ---- final residual + coalesced store
    {
        float4 o[4];
        #pragma unroll
        for (int jj = 0; jj < 4; ++jj) {
            o[jj].x = x2[4*jj+0] + __uint_as_float(lds[O_SFFN + lane*17 + 4*jj+0]);
            o[jj].y = x2[4*jj+1] + __uint_as_float(lds[O_SFFN + lane*17 + 4*jj+1]);
            o[jj].z = x2[4*jj+2] + __uint_as_float(lds[O_SFFN + lane*17 + 4*jj+2]);
            o[jj].w = x2[4*jj+3] + __uint_as_float(lds[O_SFFN + lane*17 + 4*jj+3]);
        }
        float4* op = (float4*)(out + base + (size_t)lane * 16);
        op[0] = o[0]; op[1] = o[1]; op[2] = o[2]; op[3] = o[3];
    }
}

extern "C" void kernel_launch(void* const* d_in, const int* in_sizes, int n_in,
                              void* d_out, int out_size, void* d_ws, size_t ws_size,
                              hipStream_t stream) {
    const float* x     = (const float*)d_in[0];
    const float* Wk    = (const float*)d_in[1];
    const float* Wq    = (const float*)d_in[2];
    const float* Wv    = (const float*)d_in[3];
    const float* ln1_g = (const float*)d_in[4];
    const float* ln1_b = (const float*)d_in[5];
    const float* ln2_g = (const float*)d_in[6];
    const float* ln2_b = (const float*)d_in[7];
    const float* W1    = (const float*)d_in[8];
    const float* b1    = (const float*)d_in[9];
    const float* W2    = (const float*)d_in[10];
    const float* b2    = (const float*)d_in[11];
    float* out = (float*)d_out;

    const int n_blocks = in_sizes[0] / (64 * 16);   // 16384
    tb_kernel<<<n_blocks, 64, 0, stream>>>(
        x, Wk, Wq, Wv, ln1_g, ln1_b, ln2_g, ln2_b, W1, b1, W2, b2, out);
}

// Round 2
// 226.503 us; speedup vs baseline: 1.2124x; 1.2124x over previous
//
#include <hip/hip_runtime.h>
#include <hip/hip_bf16.h>
#include <math.h>

// ---------------------------------------------------------------------------
// Fully-MFMA fused transformer block (R9):
//   - MFMA (split-4 bf16, fp32-grade) for Q/K/V projections, FFN1, FFN2
//   - MFMA attention: S^T = K.Q^T (split-3, causal triangle only, 30 MFMAs),
//     direct 64-key softmax in registers (no online rescale), y^T = V^T.P
//     (P bf16-hi, V hi/lo, 12 MFMAs). Replaces the scalar attention whose
//     512 broadcast ds_read_b128/wave made the kernel LDS-pipe-bound (~85%).
//   - TWO-PASS variance in LN1/LN2 (matches reference mean(square(x-mu))).
// One wave (64 threads) per batch block of 64 tokens x 16 channels.
// v_mfma_f32_16x16x32_bf16 layouts (m89/m91-verified):
//   C/D: D[m=quad*4+reg][n=lane&15]
//   A:   A[m=lane&15][k=quad*8+j]   (word p = elements 2p(lo16), 2p+1(hi16))
//   B:   B[k=quad*8+j][n=lane&15]
// ---------------------------------------------------------------------------

typedef __attribute__((ext_vector_type(8))) short bf8;   // 8 bf16 (4 VGPRs)
typedef __attribute__((ext_vector_type(4))) float f4;    // 4 fp32 (C/D frag)

union FragU { uint4 u4; uint u[4]; bf8 b; };

__device__ __forceinline__ uint packbf(float lo, float hi) {   // lo -> bits[15:0]
    union { __hip_bfloat162 h; uint u; } c;
    c.h = __float22bfloat162_rn(make_float2(lo, hi));
    return c.u;
}
// split pair (a,b) into bf16-hi word + bf16-lo(residual) word
__device__ __forceinline__ void split2(float a, float b, uint& h, uint& l) {
    h = packbf(a, b);
    float ra = a - __uint_as_float(h << 16);          // exact residual
    float rb = b - __uint_as_float(h & 0xFFFF0000u);
    l = packbf(ra, rb);
}

// exact-gelu via A&S 7.1.26 erf (max err 1.5e-7), branch-free
__device__ __forceinline__ float gelu_f(float u) {
    float z  = fabsf(u) * 0.70710678118654752f;
    float tt = __builtin_amdgcn_rcpf(1.f + 0.3275911f * z);
    float poly = ((((1.061405429f * tt - 1.453152027f) * tt + 1.421413741f) * tt
                   - 0.284496736f) * tt + 0.254829592f) * tt;
    float erfz = 1.f - poly * __expf(-z * z);
    return 0.5f * u * (1.f + copysignf(erfz, u));
}

#define MFMA(a, b, c) __builtin_amdgcn_mfma_f32_16x16x32_bf16(a, b, c, 0, 0, 0)

// LDS arena (word units), 3392 words = 13568 B.
//  Phase A out: sQp hi/lo [64][9]@0/576, sKp hi/lo @1152/1728,
//               sVp hi/lo [16][34]@2304/2848
//  Phase P:     sPp bf16 [64 queries][36 pairs-stride]@0 (over dead sQp+sKp)
//  Phase LN2:   sH2 hi/lo [64][12]@0/768 (over dead sPp head)
//  Phase FFN1:  sU [64][36]@0 ; Phase out: sFFN [64][20]@0
#define OQH 0
#define OQL 576
#define OKH 1152
#define OKL 1728
#define OVH 2304
#define OVL 2848
#define OP  0
#define OH2H 0
#define OH2L 768
#define OU  0
#define OF  0
#define ARENA 3392

// hi/lo split B-fragment pair: B[k=kb+j][n], row-major W, leading dim ld
__device__ __forceinline__ void loadWfragHL(const float* __restrict__ W, int ld,
                                            int n, int kb, bool valid, float scale,
                                            bf8& hf, bf8& lf) {
    FragU H, L;
    if (valid) {
        #pragma unroll
        for (int p = 0; p < 4; ++p) {
            float a = W[(kb+2*p  )*ld+n]*scale;
            float b = W[(kb+2*p+1)*ld+n]*scale;
            split2(a, b, H.u[p], L.u[p]);
        }
    } else {
        H.u4 = make_uint4(0u,0u,0u,0u);
        L.u4 = H.u4;
    }
    hf = H.b; lf = L.b;
}

__global__ __launch_bounds__(64, 3)
void tb_kernel(const float* __restrict__ x,
               const float* __restrict__ Wk, const float* __restrict__ Wq,
               const float* __restrict__ Wv,
               const float* __restrict__ ln1g, const float* __restrict__ ln1b,
               const float* __restrict__ ln2g, const float* __restrict__ ln2b,
               const float* __restrict__ W1, const float* __restrict__ b1,
               const float* __restrict__ W2, const float* __restrict__ b2,
               float* __restrict__ out)
{
    __shared__ __align__(16) uint lds[ARENA];
    const int lane = threadIdx.x;
    const int c15  = lane & 15;
    const int quad = lane >> 4;
    const int quad4 = quad << 2;
    const size_t base = (size_t)blockIdx.x * (64 * 16);
    const f4 z4 = {0.f, 0.f, 0.f, 0.f};
    const bool kv = (quad < 2);          // K=16 mats: only quads 0,1 carry data
    const int  kb = quad * 8;
    const bool wrE = ((c15 & 1) == 0);

    // ---- attention weight fragments (split hi/lo)
    bf8 fWq_h, fWq_l, fWk_h, fWk_l, fWv_h, fWv_l;
    loadWfragHL(Wq, 16, c15, kb, kv, 0.25f, fWq_h, fWq_l);  // fold 1/sqrt(D)
    loadWfragHL(Wk, 16, c15, kb, kv, 1.0f,  fWk_h, fWk_l);
    loadWfragHL(Wv, 16, c15, kb, kv, 1.0f,  fWv_h, fWv_l);

    // ---- LN1 (fp32, TWO-PASS variance) -> split hi/lo A-fragments
    bf8 ah_h[4], ah_l[4];
    {
        float gg[8], bb[8];
        if (kv) {
            const float4* gp = (const float4*)(ln1g + kb);
            const float4* bp = (const float4*)(ln1b + kb);
            float4 g0 = gp[0], g1 = gp[1], b0 = bp[0], b1_ = bp[1];
            gg[0]=g0.x; gg[1]=g0.y; gg[2]=g0.z; gg[3]=g0.w;
            gg[4]=g1.x; gg[5]=g1.y; gg[6]=g1.z; gg[7]=g1.w;
            bb[0]=b0.x; bb[1]=b0.y; bb[2]=b0.z; bb[3]=b0.w;
            bb[4]=b1_.x; bb[5]=b1_.y; bb[6]=b1_.z; bb[7]=b1_.w;
        }
        #pragma unroll
        for (int mt = 0; mt < 4; ++mt) {
            FragU Ah, Al;
            if (kv) {
                const float4* xp = (const float4*)(x + base + (size_t)(mt*16 + c15)*16 + kb);
                float4 v0 = xp[0], v1 = xp[1];
                float xv[8] = {v0.x,v0.y,v0.z,v0.w, v1.x,v1.y,v1.z,v1.w};
                float s = 0.f;
                #pragma unroll
                for (int j = 0; j < 8; ++j) s += xv[j];
                s  += __shfl_xor(s, 16);    // combine half-rows (both in quads 0,1)
                float mu = s * 0.0625f;
                float s2 = 0.f;
                #pragma unroll
                for (int j = 0; j < 8; ++j) { float d = xv[j] - mu; s2 += d*d; }
                s2 += __shfl_xor(s2, 16);   // two-pass variance: no cancellation
                float var  = s2 * 0.0625f;
                float rstd = rsqrtf(var + 1e-5f);
                float h[8];
                #pragma unroll
                for (int j = 0; j < 8; ++j) h[j] = (xv[j]-mu)*rstd*gg[j] + bb[j];
                #pragma unroll
                for (int p = 0; p < 4; ++p) split2(h[2*p], h[2*p+1], Ah.u[p], Al.u[p]);
            } else {
                Ah.u4 = make_uint4(0u,0u,0u,0u);
                Al.u4 = Ah.u4;
            }
            ah_h[mt] = Ah.b; ah_l[mt] = Al.b;
        }
    }

    // ---- projections (split-4) -> packed bf16 hi/lo LDS tiles
    //  sQp/sKp: [tok][chpair] stride 9 (word = ch 2g lo16, 2g+1 hi16)
    //  sVp:     [ch][tokpair] stride 34 (word = tok 2g lo16, 2g+1 hi16)
    #pragma unroll
    for (int mt = 0; mt < 4; ++mt) {
        f4 qc = MFMA(ah_l[mt], fWq_l, z4);
        qc = MFMA(ah_l[mt], fWq_h, qc);
        qc = MFMA(ah_h[mt], fWq_l, qc);
        qc = MFMA(ah_h[mt], fWq_h, qc);
        f4 kc = MFMA(ah_l[mt], fWk_l, z4);
        kc = MFMA(ah_l[mt], fWk_h, kc);
        kc = MFMA(ah_h[mt], fWk_l, kc);
        kc = MFMA(ah_h[mt], fWk_h, kc);
        f4 vc = MFMA(ah_l[mt], fWv_l, z4);
        vc = MFMA(ah_l[mt], fWv_h, vc);
        vc = MFMA(ah_h[mt], fWv_l, vc);
        vc = MFMA(ah_h[mt], fWv_h, vc);
        // Q,K: pair along channels via lane^1 exchange; even lanes write
        #pragma unroll
        for (int r = 0; r < 4; ++r) {
            const int tok = mt*16 + quad4 + r;
            float qo = __shfl_xor(qc[r], 1);
            float ko = __shfl_xor(kc[r], 1);
            if (wrE) {
                uint h_, l_;
                split2(qc[r], qo, h_, l_);
                lds[OQH + tok*9 + (c15>>1)] = h_;
                lds[OQL + tok*9 + (c15>>1)] = l_;
                split2(kc[r], ko, h_, l_);
                lds[OKH + tok*9 + (c15>>1)] = h_;
                lds[OKL + tok*9 + (c15>>1)] = l_;
            }
        }
        // V: pair along tokens, fully in-lane
        {
            uint h0,l0,h1,l1;
            split2(vc[0], vc[1], h0, l0);
            split2(vc[2], vc[3], h1, l1);
            const int po = c15*34 + mt*8 + quad*2;
            *(uint2*)(lds + OVH + po) = make_uint2(h0, h1);
            *(uint2*)(lds + OVL + po) = make_uint2(l0, l1);
        }
    }
    __syncthreads();   // B1: packed Q/K/V visible

    // ---- S^T = K.Q^T (split-3: KlQh + KhQl + KhQh), causal triangle only
    bf8 qbh[4], qbl[4];            // B-frags: B[k=ch][n=query] per query-tile
    #pragma unroll
    for (int qt = 0; qt < 4; ++qt) {
        FragU H, L;
        if (kv) {
            const int bo = (qt*16 + c15)*9 + quad4;
            H.u[0]=lds[OQH+bo]; H.u[1]=lds[OQH+bo+1]; H.u[2]=lds[OQH+bo+2]; H.u[3]=lds[OQH+bo+3];
            L.u[0]=lds[OQL+bo]; L.u[1]=lds[OQL+bo+1]; L.u[2]=lds[OQL+bo+2]; L.u[3]=lds[OQL+bo+3];
        } else {
            H.u4 = make_uint4(0u,0u,0u,0u); L.u4 = H.u4;
        }
        qbh[qt] = H.b; qbl[qt] = L.b;
    }
    f4 st[4][4];                   // st[kt][qt]: S^T[key=kt*16+quad4+r][query=qt*16+c15]
    #pragma unroll
    for (int kt = 0; kt < 4; ++kt) {
        FragU H, L;                // A-frag: A[m=key][k=ch]
        if (kv) {
            const int bo = (kt*16 + c15)*9 + quad4;
            H.u[0]=lds[OKH+bo]; H.u[1]=lds[OKH+bo+1]; H.u[2]=lds[OKH+bo+2]; H.u[3]=lds[OKH+bo+3];
            L.u[0]=lds[OKL+bo]; L.u[1]=lds[OKL+bo+1]; L.u[2]=lds[OKL+bo+2]; L.u[3]=lds[OKL+bo+3];
        } else {
            H.u4 = make_uint4(0u,0u,0u,0u); L.u4 = H.u4;
        }
        bf8 kah = H.b, kal = L.b;
        #pragma unroll
        for (int qt = 3; qt >= 0; --qt) {
            if (qt >= kt) {        // compile-time (unrolled): triangle only
                f4 s = MFMA(kal, qbh[qt], z4);
                s = MFMA(kah, qbl[qt], s);
                s = MFMA(kah, qbh[qt], s);
                st[kt][qt] = s;
            }
        }
    }
    // causal mask on diagonal tiles: key=qt*16+quad4+r vs query=qt*16+c15
    #pragma unroll
    for (int qt = 0; qt < 4; ++qt)
        #pragma unroll
        for (int r = 0; r < 4; ++r)
            st[qt][qt][r] = (quad4 + r <= c15) ? st[qt][qt][r] : -1e30f;

    // ---- direct softmax per query column (in-lane + cross-quad butterfly)
    float linv[4];
    #pragma unroll
    for (int qt = 0; qt < 4; ++qt) {
        float mx = st[0][qt][0];
        #pragma unroll
        for (int kt = 0; kt < 4; ++kt) {
            if (kt <= qt) {
                #pragma unroll
                for (int r = 0; r < 4; ++r) mx = fmaxf(mx, st[kt][qt][r]);
            }
        }
        mx = fmaxf(mx, __shfl_xor(mx, 16));
        mx = fmaxf(mx, __shfl_xor(mx, 32));
        float l = 0.f;
        #pragma unroll
        for (int kt = 0; kt < 4; ++kt) {
            if (kt <= qt) {
                #pragma unroll
                for (int r = 0; r < 4; ++r) {
                    float p = __expf(st[kt][qt][r] - mx);   // masked -> exp(-1e30)=0
                    st[kt][qt][r] = p;
                    l += p;
                }
            }
        }
        l += __shfl_xor(l, 16);
        l += __shfl_xor(l, 32);
        linv[qt] = 1.0f / l;       // replicated across quads; matches y layout
    }
    __syncthreads();   // B2a: Q/K frag reads done; sPp region writable

    // ---- pack P (bf16, unnormalized, in-lane key-pairs) -> sPp [query][36]
    #pragma unroll
    for (int qt = 0; qt < 4; ++qt) {
        const int rowo = OP + (qt*16 + c15)*36 + quad*2;
        #pragma unroll
        for (int kt = 0; kt < 4; ++kt) {
            uint2 w;
            if (kt <= qt) {
                w.x = packbf(st[kt][qt][0], st[kt][qt][1]);
                w.y = packbf(st[kt][qt][2], st[kt][qt][3]);
            } else w = make_uint2(0u, 0u);
            *(uint2*)(lds + rowo + kt*8) = w;
        }
    }
    __syncthreads();   // B2b: sPp visible

    // ---- y^T = V^T.P (V split hi/lo, P hi; K=64 over 2 chunks)
    bf8 vah[2], vaL[2];            // A-frag: A[m=ch][k=key]
    #pragma unroll
    for (int kc = 0; kc < 2; ++kc) {
        FragU H, L;
        const int bo = c15*34 + kc*16 + quad4;
        uint2 h0 = *(const uint2*)(lds + OVH + bo);
        uint2 h1 = *(const uint2*)(lds + OVH + bo + 2);
        uint2 l0 = *(const uint2*)(lds + OVL + bo);
        uint2 l1 = *(const uint2*)(lds + OVL + bo + 2);
        H.u[0]=h0.x; H.u[1]=h0.y; H.u[2]=h1.x; H.u[3]=h1.y;
        L.u[0]=l0.x; L.u[1]=l0.y; L.u[2]=l1.x; L.u[3]=l1.y;
        vah[kc] = H.b; vaL[kc] = L.b;
    }
    f4 yt[4];                      // yt[qt]: y[query=qt*16+c15][ch=quad4+r] (unnorm)
    #pragma unroll
    for (int qt = 0; qt < 4; ++qt) {
        f4 acc = z4;
        #pragma unroll
        for (int kc = 0; kc < 2; ++kc) {
            if (kc == 0 || qt >= 2) {   // chunk1 (keys>=32) only for queries>=32
                FragU P_;
                P_.u4 = *(const uint4*)(lds + OP + (qt*16 + c15)*36 + kc*16 + quad4);
                acc = MFMA(vaL[kc], P_.b, acc);
                acc = MFMA(vah[kc], P_.b, acc);
            }
        }
        yt[qt] = acc;
    }

    // ---- residual 1 (y layout: query=qt*16+c15, ch=quad4+r)
    float x2v[4][4];
    #pragma unroll
    for (int qt = 0; qt < 4; ++qt) {
        float4 xv = *(const float4*)(x + base + (size_t)(qt*16 + c15)*16 + quad4);
        const float li = linv[qt];
        x2v[qt][0] = xv.x + yt[qt][0]*li;
        x2v[qt][1] = xv.y + yt[qt][1]*li;
        x2v[qt][2] = xv.z + yt[qt][2]*li;
        x2v[qt][3] = xv.w + yt[qt][3]*li;
    }
    __syncthreads();   // B3: sPp/sVp reads done; sH2 region writable

    // ---- LN2 (two-pass, cross-quad butterfly) -> packed h2 hi/lo
    {
        float4 g2  = *(const float4*)(ln2g + quad4);
        float4 b2v = *(const float4*)(ln2b + quad4);
        #pragma unroll
        for (int qt = 0; qt < 4; ++qt) {
            float s = x2v[qt][0]+x2v[qt][1]+x2v[qt][2]+x2v[qt][3];
            s += __shfl_xor(s, 16); s += __shfl_xor(s, 32);
            float mu = s * 0.0625f;
            float d0 = x2v[qt][0]-mu, d1 = x2v[qt][1]-mu,
                  d2 = x2v[qt][2]-mu, d3 = x2v[qt][3]-mu;
            float s2 = d0*d0 + d1*d1 + d2*d2 + d3*d3;
            s2 += __shfl_xor(s2, 16); s2 += __shfl_xor(s2, 32);
            float rstd = rsqrtf(s2 * 0.0625f + 1e-5f);
            float h0 = d0*rstd*g2.x + b2v.x;
            float h1 = d1*rstd*g2.y + b2v.y;
            float h2_ = d2*rstd*g2.z + b2v.z;
            float h3 = d3*rstd*g2.w + b2v.w;
            uint hw0, lw0, hw1, lw1;
            split2(h0, h1, hw0, lw0);
            split2(h2_, h3, hw1, lw1);
            const int ro = (qt*16 + c15)*12 + quad*2;
            *(uint2*)(lds + OH2H + ro) = make_uint2(hw0, hw1);
            *(uint2*)(lds + OH2L + ro) = make_uint2(lw0, lw1);
        }
    }
    __syncthreads();   // B4: sH2 visible

    // ---- h2 A-fragments
    bf8 a2h[4], a2l[4];
    #pragma unroll
    for (int i = 0; i < 4; ++i) {
        FragU H, L;
        if (kv) {
            const int bo = (i*16 + c15)*12 + quad4;
            H.u4 = *(const uint4*)(lds + OH2H + bo);
            L.u4 = *(const uint4*)(lds + OH2L + bo);
        } else {
            H.u4 = make_uint4(0u,0u,0u,0u);
            L.u4 = H.u4;
        }
        a2h[i] = H.b; a2l[i] = L.b;
    }
    __syncthreads();   // B5: sH2 dead; sU region writable

    // ---- FFN weight fragments
    bf8 fW1a_h, fW1a_l, fW1b_h, fW1b_l, fW2_h, fW2_l;
    loadWfragHL(W1, 32, c15,      kb, kv,   1.0f, fW1a_h, fW1a_l);
    loadWfragHL(W1, 32, c15 + 16, kb, kv,   1.0f, fW1b_h, fW1b_l);
    loadWfragHL(W2, 16, c15,      kb, true, 1.0f, fW2_h,  fW2_l);

    // ---- FFN1 (split-4) + gelu -> sU hi/lo [64][36]
    {
        float bu0 = b1[c15], bu1 = b1[16 + c15];
        f4 cb0 = {bu0, bu0, bu0, bu0};
        f4 cb1 = {bu1, bu1, bu1, bu1};
        f4 uu[4][2];
        #pragma unroll
        for (int mt = 0; mt < 4; ++mt) {
            f4 u0 = MFMA(a2l[mt], fW1a_l, cb0);
            u0 = MFMA(a2l[mt], fW1a_h, u0);
            u0 = MFMA(a2h[mt], fW1a_l, u0);
            uu[mt][0] = MFMA(a2h[mt], fW1a_h, u0);
            f4 u1 = MFMA(a2l[mt], fW1b_l, cb1);
            u1 = MFMA(a2l[mt], fW1b_h, u1);
            u1 = MFMA(a2h[mt], fW1b_l, u1);
            uu[mt][1] = MFMA(a2h[mt], fW1b_h, u1);
        }
        #pragma unroll
        for (int mt = 0; mt < 4; ++mt)
            #pragma unroll
            for (int nt = 0; nt < 2; ++nt)
                #pragma unroll
                for (int r = 0; r < 4; ++r) {
                    float g  = gelu_f(uu[mt][nt][r]);
                    float go = __shfl_xor(g, 1);
                    if (wrE) {
                        uint hw, lw;
                        split2(g, go, hw, lw);
                        const int row = mt*16 + quad4 + r;
                        lds[OU + row*36 +      nt*8 + (c15 >> 1)] = hw;
                        lds[OU + row*36 + 16 + nt*8 + (c15 >> 1)] = lw;
                    }
                }
    }
    __syncthreads();   // B6: sU visible

    // ---- FFN2 (split-4, K=32 full)
    f4 fo[4];
    {
        float bo = b2[c15];
        f4 cb = {bo, bo, bo, bo};
        #pragma unroll
        for (int mt = 0; mt < 4; ++mt) {
            FragU H, L;
            const int off = (mt*16 + c15)*36;
            H.u4 = *(const uint4*)(lds + OU + off +      quad4);
            L.u4 = *(const uint4*)(lds + OU + off + 16 + quad4);
            f4 f0 = MFMA(L.b, fW2_l, cb);
            f0 = MFMA(L.b, fW2_h, f0);
            f0 = MFMA(H.b, fW2_l, f0);
            fo[mt] = MFMA(H.b, fW2_h, f0);
        }
    }
    __syncthreads();   // B7: sU dead; sFFN writable
    #pragma unroll
    for (int mt = 0; mt < 4; ++mt)
        #pragma unroll
        for (int r = 0; r < 4; ++r)
            lds[OF + (mt*16 + quad4 + r)*20 + c15] = __float_as_uint(fo[mt][r]);
    __syncthreads();   // B8: sFFN visible

    // ---- final residual + coalesced store (y layout, b128 per query-tile)
    #pragma unroll
    for (int qt = 0; qt < 4; ++qt) {
        FragU F;
        F.u4 = *(const uint4*)(lds + OF + (qt*16 + c15)*20 + quad4);
        float4 o;
        o.x = x2v[qt][0] + __uint_as_float(F.u[0]);
        o.y = x2v[qt][1] + __uint_as_float(F.u[1]);
        o.z = x2v[qt][2] + __uint_as_float(F.u[2]);
        o.w = x2v[qt][3] + __uint_as_float(F.u[3]);
        *(float4*)(out + base + (size_t)(qt*16 + c15)*16 + quad4) = o;
    }
}

extern "C" void kernel_launch(void* const* d_in, const int* in_sizes, int n_in,
                              void* d_out, int out_size, void* d_ws, size_t ws_size,
                              hipStream_t stream) {
    const float* x     = (const float*)d_in[0];
    const float* Wk    = (const float*)d_in[1];
    const float* Wq    = (const float*)d_in[2];
    const float* Wv    = (const float*)d_in[3];
    const float* ln1_g = (const float*)d_in[4];
    const float* ln1_b = (const float*)d_in[5];
    const float* ln2_g = (const float*)d_in[6];
    const float* ln2_b = (const float*)d_in[7];
    const float* W1    = (const float*)d_in[8];
    const float* b1    = (const float*)d_in[9];
    const float* W2    = (const float*)d_in[10];
    const float* b2    = (const float*)d_in[11];
    float* out = (float*)d_out;

    const int n_blocks = in_sizes[0] / (64 * 16);   // 16384
    tb_kernel<<<n_blocks, 64, 0, stream>>>(
        x, Wk, Wq, Wv, ln1_g, ln1_b, ln2_g, ln2_b, W1, b1, W2, b2, out);
}

// Round 3
// 185.547 us; speedup vs baseline: 1.4801x; 1.2207x over previous
//
#include <hip/hip_runtime.h>
#include <hip/hip_bf16.h>
#include <math.h>

// ---------------------------------------------------------------------------
// Fully-MFMA fused transformer block (R10 = R9 minus hi/lo split machinery):
//   All GEMMs single-bf16 (error budget: threshold 0.11, R9 absmax 0.031 was
//   already the output-bf16 quantization floor; bf16 inputs add <= ~0.02).
//   Softmax/LN/residual/gelu stay fp32 with two-pass variance.
//   MFMA count 138 -> 40; LDS arena 13568 -> 9216 B => 11 -> 17 blocks/CU
//   (kernel is latency-bound: ~85% of wave lifetime was stall at occ 27%).
// One wave (64 threads) per batch block of 64 tokens x 16 channels.
// v_mfma_f32_16x16x32_bf16 layouts (m89/m91-verified):
//   C/D: D[m=quad*4+reg][n=lane&15]
//   A:   A[m=lane&15][k=quad*8+j]   (word p = elements 2p(lo16), 2p+1(hi16))
//   B:   B[k=quad*8+j][n=lane&15]
// ---------------------------------------------------------------------------

typedef __attribute__((ext_vector_type(8))) short bf8;   // 8 bf16 (4 VGPRs)
typedef __attribute__((ext_vector_type(4))) float f4;    // 4 fp32 (C/D frag)

union FragU { uint4 u4; uint u[4]; bf8 b; };

__device__ __forceinline__ uint packbf(float lo, float hi) {   // lo -> bits[15:0]
    union { __hip_bfloat162 h; uint u; } c;
    c.h = __float22bfloat162_rn(make_float2(lo, hi));
    return c.u;
}

// exact-gelu via A&S 7.1.26 erf (max err 1.5e-7), branch-free
__device__ __forceinline__ float gelu_f(float u) {
    float z  = fabsf(u) * 0.70710678118654752f;
    float tt = __builtin_amdgcn_rcpf(1.f + 0.3275911f * z);
    float poly = ((((1.061405429f * tt - 1.453152027f) * tt + 1.421413741f) * tt
                   - 0.284496736f) * tt + 0.254829592f) * tt;
    float erfz = 1.f - poly * __expf(-z * z);
    return 0.5f * u * (1.f + copysignf(erfz, u));
}

#define MFMA(a, b, c) __builtin_amdgcn_mfma_f32_16x16x32_bf16(a, b, c, 0, 0, 0)

// LDS arena (word units), 2304 words = 9216 B. Regions (words):
//  Phase A out: sQ bf16-pairs [64][12] @0, sK [64][12] @768, sV [16][36] @1536
//  Phase P:     sP bf16 [64 queries][36] @0 (V already in regs; over dead Q/K)
//  Phase LN2:   sH2 [64][12] @0          (over dead sP head)
//  Phase FFN1:  sU [64][20] @768         (over dead sK/sV/sP)
//  Phase out:   sF f32 [64][20] @0       (over dead sH2 + sU head)
#define OQ  0
#define OK  768
#define OV  1536
#define OP  0
#define OH2 0
#define OU  768
#define OF  0
#define ARENA 2304

// bf16 B-fragment: B[k=kb+j][n], row-major W, leading dim ld
__device__ __forceinline__ void loadWfrag(const float* __restrict__ W, int ld,
                                          int n, int kb, bool valid, float scale,
                                          bf8& hf) {
    FragU H;
    if (valid) {
        #pragma unroll
        for (int p = 0; p < 4; ++p)
            H.u[p] = packbf(W[(kb+2*p)*ld+n]*scale, W[(kb+2*p+1)*ld+n]*scale);
    } else {
        H.u4 = make_uint4(0u,0u,0u,0u);
    }
    hf = H.b;
}

__global__ __launch_bounds__(64, 4)
void tb_kernel(const float* __restrict__ x,
               const float* __restrict__ Wk, const float* __restrict__ Wq,
               const float* __restrict__ Wv,
               const float* __restrict__ ln1g, const float* __restrict__ ln1b,
               const float* __restrict__ ln2g, const float* __restrict__ ln2b,
               const float* __restrict__ W1, const float* __restrict__ b1,
               const float* __restrict__ W2, const float* __restrict__ b2,
               float* __restrict__ out)
{
    __shared__ __align__(16) uint lds[ARENA];
    const int lane = threadIdx.x;
    const int c15  = lane & 15;
    const int quad = lane >> 4;
    const int quad4 = quad << 2;
    const size_t base = (size_t)blockIdx.x * (64 * 16);
    const f4 z4 = {0.f, 0.f, 0.f, 0.f};
    const bool kv = (quad < 2);          // K=16 mats: only quads 0,1 carry data
    const int  kb = quad * 8;
    const bool wrE = ((c15 & 1) == 0);

    // ---- attention weight fragments (bf16)
    bf8 fWq, fWk, fWv;
    loadWfrag(Wq, 16, c15, kb, kv, 0.25f, fWq);  // fold 1/sqrt(D)
    loadWfrag(Wk, 16, c15, kb, kv, 1.0f,  fWk);
    loadWfrag(Wv, 16, c15, kb, kv, 1.0f,  fWv);

    // ---- LN1 (fp32, TWO-PASS variance) -> bf16 A-fragments
    bf8 ah[4];
    {
        float gg[8], bb[8];
        if (kv) {
            const float4* gp = (const float4*)(ln1g + kb);
            const float4* bp = (const float4*)(ln1b + kb);
            float4 g0 = gp[0], g1 = gp[1], b0 = bp[0], b1_ = bp[1];
            gg[0]=g0.x; gg[1]=g0.y; gg[2]=g0.z; gg[3]=g0.w;
            gg[4]=g1.x; gg[5]=g1.y; gg[6]=g1.z; gg[7]=g1.w;
            bb[0]=b0.x; bb[1]=b0.y; bb[2]=b0.z; bb[3]=b0.w;
            bb[4]=b1_.x; bb[5]=b1_.y; bb[6]=b1_.z; bb[7]=b1_.w;
        }
        #pragma unroll
        for (int mt = 0; mt < 4; ++mt) {
            FragU Ah;
            if (kv) {
                const float4* xp = (const float4*)(x + base + (size_t)(mt*16 + c15)*16 + kb);
                float4 v0 = xp[0], v1 = xp[1];
                float xv[8] = {v0.x,v0.y,v0.z,v0.w, v1.x,v1.y,v1.z,v1.w};
                float s = 0.f;
                #pragma unroll
                for (int j = 0; j < 8; ++j) s += xv[j];
                s  += __shfl_xor(s, 16);    // combine half-rows (both in quads 0,1)
                float mu = s * 0.0625f;
                float s2 = 0.f;
                #pragma unroll
                for (int j = 0; j < 8; ++j) { float d = xv[j] - mu; s2 += d*d; }
                s2 += __shfl_xor(s2, 16);   // two-pass variance: no cancellation
                float var  = s2 * 0.0625f;
                float rstd = rsqrtf(var + 1e-5f);
                float h[8];
                #pragma unroll
                for (int j = 0; j < 8; ++j) h[j] = (xv[j]-mu)*rstd*gg[j] + bb[j];
                #pragma unroll
                for (int p = 0; p < 4; ++p) Ah.u[p] = packbf(h[2*p], h[2*p+1]);
            } else {
                Ah.u4 = make_uint4(0u,0u,0u,0u);
            }
            ah[mt] = Ah.b;
        }
    }

    // ---- projections -> packed bf16 LDS tiles
    //  sQ/sK: [tok][chpair] stride 12; sV: [ch][tokpair] stride 36
    #pragma unroll
    for (int mt = 0; mt < 4; ++mt) {
        f4 qc = MFMA(ah[mt], fWq, z4);
        f4 kc = MFMA(ah[mt], fWk, z4);
        f4 vc = MFMA(ah[mt], fWv, z4);
        #pragma unroll
        for (int r = 0; r < 4; ++r) {
            const int tok = mt*16 + quad4 + r;
            float qo = __shfl_xor(qc[r], 1);
            float ko = __shfl_xor(kc[r], 1);
            if (wrE) {
                lds[OQ + tok*12 + (c15>>1)] = packbf(qc[r], qo);
                lds[OK + tok*12 + (c15>>1)] = packbf(kc[r], ko);
            }
        }
        *(uint2*)(lds + OV + c15*36 + mt*8 + quad*2) =
            make_uint2(packbf(vc[0], vc[1]), packbf(vc[2], vc[3]));
    }
    __syncthreads();   // B1: packed Q/K/V visible

    // ---- S^T = K.Q^T, causal triangle only (10 MFMAs)
    bf8 qb[4];                     // B-frags: B[k=ch][n=query] per query-tile
    #pragma unroll
    for (int qt = 0; qt < 4; ++qt) {
        FragU H;
        if (kv) H.u4 = *(const uint4*)(lds + OQ + (qt*16 + c15)*12 + quad4);
        else    H.u4 = make_uint4(0u,0u,0u,0u);
        qb[qt] = H.b;
    }
    f4 st[4][4];                   // st[kt][qt]: S^T[key=kt*16+quad4+r][query=qt*16+c15]
    #pragma unroll
    for (int kt = 0; kt < 4; ++kt) {
        FragU H;                   // A-frag: A[m=key][k=ch]
        if (kv) H.u4 = *(const uint4*)(lds + OK + (kt*16 + c15)*12 + quad4);
        else    H.u4 = make_uint4(0u,0u,0u,0u);
        bf8 ka = H.b;
        #pragma unroll
        for (int qt = 3; qt >= 0; --qt)
            if (qt >= kt)          // compile-time (unrolled): triangle only
                st[kt][qt] = MFMA(ka, qb[qt], z4);
    }
    // causal mask on diagonal tiles: key=qt*16+quad4+r vs query=qt*16+c15
    #pragma unroll
    for (int qt = 0; qt < 4; ++qt)
        #pragma unroll
        for (int r = 0; r < 4; ++r)
            st[qt][qt][r] = (quad4 + r <= c15) ? st[qt][qt][r] : -1e30f;

    // ---- direct softmax per query column (in-lane + cross-quad butterfly)
    float linv[4];
    #pragma unroll
    for (int qt = 0; qt < 4; ++qt) {
        float mx = st[0][qt][0];
        #pragma unroll
        for (int kt = 0; kt < 4; ++kt) {
            if (kt <= qt) {
                #pragma unroll
                for (int r = 0; r < 4; ++r) mx = fmaxf(mx, st[kt][qt][r]);
            }
        }
        mx = fmaxf(mx, __shfl_xor(mx, 16));
        mx = fmaxf(mx, __shfl_xor(mx, 32));
        float l = 0.f;
        #pragma unroll
        for (int kt = 0; kt < 4; ++kt) {
            if (kt <= qt) {
                #pragma unroll
                for (int r = 0; r < 4; ++r) {
                    float p = __expf(st[kt][qt][r] - mx);   // masked -> 0
                    st[kt][qt][r] = p;
                    l += p;
                }
            }
        }
        l += __shfl_xor(l, 16);
        l += __shfl_xor(l, 32);
        linv[qt] = 1.0f / l;       // replicated across quads; matches y layout
    }

    // ---- V A-fragments into registers BEFORE sP overwrites the arena
    bf8 va[2];                     // A[m=ch][k=key], chunk kc covers keys kc*32..+31
    #pragma unroll
    for (int kc = 0; kc < 2; ++kc) {
        FragU H;
        H.u4 = *(const uint4*)(lds + OV + c15*36 + kc*16 + quad4);
        va[kc] = H.b;
    }
    __syncthreads();   // B2a: all Q/K/V reads done; sP region writable

    // ---- pack P (bf16, unnormalized, in-lane key-pairs) -> sP [query][36]
    #pragma unroll
    for (int qt = 0; qt < 4; ++qt) {
        const int rowo = OP + (qt*16 + c15)*36 + quad*2;
        #pragma unroll
        for (int kt = 0; kt < 4; ++kt) {
            uint2 w;
            if (kt <= qt) {
                w.x = packbf(st[kt][qt][0], st[kt][qt][1]);
                w.y = packbf(st[kt][qt][2], st[kt][qt][3]);
            } else w = make_uint2(0u, 0u);
            *(uint2*)(lds + rowo + kt*8) = w;
        }
    }
    __syncthreads();   // B2b: sP visible

    // ---- y^T = V^T.P (6 MFMAs)
    f4 yt[4];                      // yt[qt]: y[query=qt*16+c15][ch=quad4+r] (unnorm)
    #pragma unroll
    for (int qt = 0; qt < 4; ++qt) {
        f4 acc = z4;
        #pragma unroll
        for (int kc = 0; kc < 2; ++kc) {
            if (kc == 0 || qt >= 2) {   // chunk1 (keys>=32) only for queries>=32
                FragU P_;
                P_.u4 = *(const uint4*)(lds + OP + (qt*16 + c15)*36 + kc*16 + quad4);
                acc = MFMA(va[kc], P_.b, acc);
            }
        }
        yt[qt] = acc;
    }

    // ---- residual 1 (y layout: query=qt*16+c15, ch=quad4+r)
    float x2v[4][4];
    #pragma unroll
    for (int qt = 0; qt < 4; ++qt) {
        float4 xv = *(const float4*)(x + base + (size_t)(qt*16 + c15)*16 + quad4);
        const float li = linv[qt];
        x2v[qt][0] = xv.x + yt[qt][0]*li;
        x2v[qt][1] = xv.y + yt[qt][1]*li;
        x2v[qt][2] = xv.z + yt[qt][2]*li;
        x2v[qt][3] = xv.w + yt[qt][3]*li;
    }
    __syncthreads();   // B3: sP reads done; sH2 region writable

    // ---- LN2 (two-pass, cross-quad butterfly) -> packed bf16 h2
    {
        float4 g2  = *(const float4*)(ln2g + quad4);
        float4 b2v = *(const float4*)(ln2b + quad4);
        #pragma unroll
        for (int qt = 0; qt < 4; ++qt) {
            float s = x2v[qt][0]+x2v[qt][1]+x2v[qt][2]+x2v[qt][3];
            s += __shfl_xor(s, 16); s += __shfl_xor(s, 32);
            float mu = s * 0.0625f;
            float d0 = x2v[qt][0]-mu, d1 = x2v[qt][1]-mu,
                  d2 = x2v[qt][2]-mu, d3 = x2v[qt][3]-mu;
            float s2 = d0*d0 + d1*d1 + d2*d2 + d3*d3;
            s2 += __shfl_xor(s2, 16); s2 += __shfl_xor(s2, 32);
            float rstd = rsqrtf(s2 * 0.0625f + 1e-5f);
            float h0 = d0*rstd*g2.x + b2v.x;
            float h1 = d1*rstd*g2.y + b2v.y;
            float h2_ = d2*rstd*g2.z + b2v.z;
            float h3 = d3*rstd*g2.w + b2v.w;
            *(uint2*)(lds + OH2 + (qt*16 + c15)*12 + quad*2) =
                make_uint2(packbf(h0, h1), packbf(h2_, h3));
        }
    }
    __syncthreads();   // B4: sH2 visible

    // ---- h2 A-fragments
    bf8 a2[4];
    #pragma unroll
    for (int i = 0; i < 4; ++i) {
        FragU H;
        if (kv) H.u4 = *(const uint4*)(lds + OH2 + (i*16 + c15)*12 + quad4);
        else    H.u4 = make_uint4(0u,0u,0u,0u);
        a2[i] = H.b;
    }

    // ---- FFN weight fragments (bf16)
    bf8 fW1a, fW1b, fW2;
    loadWfrag(W1, 32, c15,      kb, kv,   1.0f, fW1a);
    loadWfrag(W1, 32, c15 + 16, kb, kv,   1.0f, fW1b);
    loadWfrag(W2, 16, c15,      kb, true, 1.0f, fW2);   // K=32 native, all quads

    // ---- FFN1 (8 MFMAs) + gelu -> sU [64][20] @768 (disjoint from sH2)
    {
        float bu0 = b1[c15], bu1 = b1[16 + c15];
        f4 cb0 = {bu0, bu0, bu0, bu0};
        f4 cb1 = {bu1, bu1, bu1, bu1};
        #pragma unroll
        for (int mt = 0; mt < 4; ++mt) {
            f4 u0 = MFMA(a2[mt], fW1a, cb0);
            f4 u1 = MFMA(a2[mt], fW1b, cb1);
            #pragma unroll
            for (int r = 0; r < 4; ++r) {
                float g0 = gelu_f(u0[r]);
                float g1 = gelu_f(u1[r]);
                float go0 = __shfl_xor(g0, 1);
                float go1 = __shfl_xor(g1, 1);
                if (wrE) {
                    const int row = mt*16 + quad4 + r;
                    lds[OU + row*20 +     (c15 >> 1)] = packbf(g0, go0);
                    lds[OU + row*20 + 8 + (c15 >> 1)] = packbf(g1, go1);
                }
            }
        }
    }
    __syncthreads();   // B5: sU visible

    // ---- FFN2 (native K=32, 4 MFMAs)
    f4 fo[4];
    {
        float bo = b2[c15];
        f4 cb = {bo, bo, bo, bo};
        #pragma unroll
        for (int mt = 0; mt < 4; ++mt) {
            FragU H;                // A[m=tok][k=quad*8+j] spans all 32 ff dims
            H.u4 = *(const uint4*)(lds + OU + (mt*16 + c15)*20 + quad4);
            fo[mt] = MFMA(H.b, fW2, cb);
        }
    }
    __syncthreads();   // B6: sU reads done; sF @0 writable (sH2 long dead)
    #pragma unroll
    for (int mt = 0; mt < 4; ++mt)
        #pragma unroll
        for (int r = 0; r < 4; ++r)
            lds[OF + (mt*16 + quad4 + r)*20 + c15] = __float_as_uint(fo[mt][r]);
    __syncthreads();   // B7: sF visible

    // ---- final residual + store (wave covers contiguous 4KB per qt tile)
    #pragma unroll
    for (int qt = 0; qt < 4; ++qt) {
        FragU F;
        F.u4 = *(const uint4*)(lds + OF + (qt*16 + c15)*20 + quad4);
        float4 o;
        o.x = x2v[qt][0] + __uint_as_float(F.u[0]);
        o.y = x2v[qt][1] + __uint_as_float(F.u[1]);
        o.z = x2v[qt][2] + __uint_as_float(F.u[2]);
        o.w = x2v[qt][3] + __uint_as_float(F.u[3]);
        *(float4*)(out + base + (size_t)(qt*16 + c15)*16 + quad4) = o;
    }
}

extern "C" void kernel_launch(void* const* d_in, const int* in_sizes, int n_in,
                              void* d_out, int out_size, void* d_ws, size_t ws_size,
                              hipStream_t stream) {
    const float* x     = (const float*)d_in[0];
    const float* Wk    = (const float*)d_in[1];
    const float* Wq    = (const float*)d_in[2];
    const float* Wv    = (const float*)d_in[3];
    const float* ln1_g = (const float*)d_in[4];
    const float* ln1_b = (const float*)d_in[5];
    const float* ln2_g = (const float*)d_in[6];
    const float* ln2_b = (const float*)d_in[7];
    const float* W1    = (const float*)d_in[8];
    const float* b1    = (const float*)d_in[9];
    const float* W2    = (const float*)d_in[10];
    const float* b2    = (const float*)d_in[11];
    float* out = (float*)d_out;

    const int n_blocks = in_sizes[0] / (64 * 16);   // 16384
    tb_kernel<<<n_blocks, 64, 0, stream>>>(
        x, Wk, Wq, Wv, ln1_g, ln1_b, ln2_g, ln2_b, W1, b1, W2, b2, out);
}